// Round 1
// baseline (712.972 us; speedup 1.0000x reference)
//
#include <hip/hip_runtime.h>

#define HDIM 256
#define DDIM 128
#define VSZ 14

// ---------- degree / CSR construction ----------

__global__ void k_count(const int* __restrict__ dst, int* __restrict__ cnt, int E) {
  int i = blockIdx.x * 256 + threadIdx.x;
  if (i < E) atomicAdd(&cnt[dst[i]], 1);
}

__global__ void k_dinv(const int* __restrict__ cnt, float* __restrict__ dinv, int n) {
  int i = blockIdx.x * 256 + threadIdx.x;
  if (i < n) dinv[i] = rsqrtf((float)(cnt[i] + 1));  // +1 self-loop
}

__global__ void k_scan_chunk(const int* __restrict__ cnt, int* __restrict__ off,
                             int* __restrict__ bsum, int n) {
  __shared__ int s[256];
  int i = blockIdx.x * 256 + threadIdx.x;
  int v = (i < n) ? cnt[i] : 0;
  s[threadIdx.x] = v;
  __syncthreads();
  for (int d = 1; d < 256; d <<= 1) {
    int add = (threadIdx.x >= d) ? s[threadIdx.x - d] : 0;
    __syncthreads();
    s[threadIdx.x] += add;
    __syncthreads();
  }
  if (i < n) off[i] = s[threadIdx.x] - v;  // exclusive prefix within chunk
  if (threadIdx.x == 255) bsum[blockIdx.x] = s[255];
}

__global__ void k_scan_bsum(int* bsum, int nb) {
  if (threadIdx.x == 0) {
    int acc = 0;
    for (int b = 0; b < nb; ++b) { int t = bsum[b]; bsum[b] = acc; acc += t; }
  }
}

__global__ void k_scan_add(int* __restrict__ off, const int* __restrict__ bsum, int n, int E) {
  int i = blockIdx.x * 256 + threadIdx.x;
  if (i < n) off[i] += bsum[i >> 8];
  else if (i == n) off[n] = E;
}

__global__ void k_fill(const int* __restrict__ src, const int* __restrict__ dst,
                       const int* __restrict__ ids, const float* __restrict__ dinv,
                       const int* __restrict__ off, int* __restrict__ cur,
                       int* __restrict__ csr_src, float* __restrict__ csr_w,
                       int* __restrict__ csr_id, int E) {
  int i = blockIdx.x * 256 + threadIdx.x;
  if (i >= E) return;
  int d = dst[i];
  int p = off[d] + atomicAdd(&cur[d], 1);
  int s = src[i];
  csr_src[p] = s;
  csr_w[p] = dinv[s];
  csr_id[p] = ids[s];
}

// ---------- tiny precomputes ----------

// embW[t][j] = sum_k emb[t][k] * W0[k][j]   (14 x 256)
__global__ void k_embw(const float* __restrict__ emb, const float* __restrict__ W0,
                       float* __restrict__ embW) {
  int t = blockIdx.x, j = threadIdx.x;
  float acc = 0.f;
  for (int k = 0; k < HDIM; ++k) acc = fmaf(emb[t * HDIM + k], W0[k * HDIM + j], acc);
  embW[t * HDIM + j] = acc;
}

// A = gamma * rsqrt(var+eps);  B = (b - mean)*A + beta
__global__ void k_bnc(const float* __restrict__ bs, const float* __restrict__ g,
                      const float* __restrict__ be, const float* __restrict__ mu,
                      const float* __restrict__ va, float* __restrict__ A,
                      float* __restrict__ B) {
  int i = blockIdx.x * HDIM + threadIdx.x;
  float a = g[i] * rsqrtf(va[i] + 1e-5f);
  A[i] = a;
  B[i] = (bs[i] - mu[i]) * a + be[i];
}

// ---------- layer 1 fused: aggregate embW rows + BN + ReLU ----------

__global__ __launch_bounds__(256) void k_layer1(
    const int* __restrict__ ids, const float* __restrict__ embW,
    const int* __restrict__ off, const int* __restrict__ csr_id,
    const float* __restrict__ csr_w, const float* __restrict__ dinv,
    const float* __restrict__ A, const float* __restrict__ B,
    float* __restrict__ Y, int n) {
  __shared__ float lw[VSZ * HDIM];
  for (int i = threadIdx.x; i < VSZ * HDIM; i += 256) lw[i] = embW[i];
  __syncthreads();
  int v = blockIdx.x * 4 + (threadIdx.x >> 6);
  if (v >= n) return;
  int j = (threadIdx.x & 63) * 4;
  float dv = dinv[v];
  float s = dv * dv;
  float4 e4 = *reinterpret_cast<const float4*>(&lw[ids[v] * HDIM + j]);
  float4 acc = make_float4(s * e4.x, s * e4.y, s * e4.z, s * e4.w);
  int e1 = off[v + 1];
  for (int e = off[v]; e < e1; ++e) {
    float w = dv * csr_w[e];
    float4 m = *reinterpret_cast<const float4*>(&lw[csr_id[e] * HDIM + j]);
    acc.x = fmaf(w, m.x, acc.x);
    acc.y = fmaf(w, m.y, acc.y);
    acc.z = fmaf(w, m.z, acc.z);
    acc.w = fmaf(w, m.w, acc.w);
  }
  float4 a4 = *reinterpret_cast<const float4*>(&A[j]);
  float4 b4 = *reinterpret_cast<const float4*>(&B[j]);
  float4 o;
  o.x = fmaxf(fmaf(acc.x, a4.x, b4.x), 0.f);
  o.y = fmaxf(fmaf(acc.y, a4.y, b4.y), 0.f);
  o.z = fmaxf(fmaf(acc.z, a4.z, b4.z), 0.f);
  o.w = fmaxf(fmaf(acc.w, a4.w, b4.w), 0.f);
  *reinterpret_cast<float4*>(&Y[(size_t)v * HDIM + j]) = o;
}

// ---------- generic aggregation: Y[v] = dinv[v]^2*X[v] + dinv[v]*sum_e dinv[src]*X[src] ----------

__global__ __launch_bounds__(256) void k_agg(
    const float* __restrict__ X, const int* __restrict__ off,
    const int* __restrict__ csr_src, const float* __restrict__ csr_w,
    const float* __restrict__ dinv, float* __restrict__ Y, int n) {
  int v = blockIdx.x * 4 + (threadIdx.x >> 6);
  if (v >= n) return;
  int j = (threadIdx.x & 63) * 4;
  float dv = dinv[v];
  float s = dv * dv;
  float4 x4 = *reinterpret_cast<const float4*>(&X[(size_t)v * HDIM + j]);
  float4 acc = make_float4(s * x4.x, s * x4.y, s * x4.z, s * x4.w);
  int e1 = off[v + 1];
  for (int e = off[v]; e < e1; ++e) {
    float w = dv * csr_w[e];
    float4 m = *reinterpret_cast<const float4*>(&X[(size_t)csr_src[e] * HDIM + j]);
    acc.x = fmaf(w, m.x, acc.x);
    acc.y = fmaf(w, m.y, acc.y);
    acc.z = fmaf(w, m.z, acc.z);
    acc.w = fmaf(w, m.w, acc.w);
  }
  *reinterpret_cast<float4*>(&Y[(size_t)v * HDIM + j]) = acc;
}

// ---------- GEMM (M x 256) @ (256 x 256) with fused BN+ReLU epilogue ----------

__global__ __launch_bounds__(256) void k_gemm(
    const float* __restrict__ X, const float* __restrict__ W,
    const float* __restrict__ A, const float* __restrict__ B,
    float* __restrict__ Y, int M) {
  __shared__ float As[16][64];
  __shared__ float Bs[16][64];
  int bm = blockIdx.x * 64;
  int bn = blockIdx.y * 64;
  int t = threadIdx.x;
  int tx = t & 15, ty = t >> 4;
  int ar = t >> 2, ak = (t & 3) * 4;
  int bk = t >> 4, bn4 = (t & 15) * 4;
  float acc[4][4] = {};
  int arow = bm + ar;
  for (int k0 = 0; k0 < HDIM; k0 += 16) {
    float4 a4 = make_float4(0.f, 0.f, 0.f, 0.f);
    if (arow < M) a4 = *reinterpret_cast<const float4*>(&X[(size_t)arow * HDIM + k0 + ak]);
    As[ak + 0][ar] = a4.x;
    As[ak + 1][ar] = a4.y;
    As[ak + 2][ar] = a4.z;
    As[ak + 3][ar] = a4.w;
    *reinterpret_cast<float4*>(&Bs[bk][bn4]) =
        *reinterpret_cast<const float4*>(&W[(size_t)(k0 + bk) * HDIM + bn + bn4]);
    __syncthreads();
#pragma unroll
    for (int kk = 0; kk < 16; ++kk) {
      float4 av = *reinterpret_cast<const float4*>(&As[kk][ty * 4]);
      float4 bv = *reinterpret_cast<const float4*>(&Bs[kk][tx * 4]);
      float a[4] = {av.x, av.y, av.z, av.w};
      float b[4] = {bv.x, bv.y, bv.z, bv.w};
#pragma unroll
      for (int i = 0; i < 4; ++i)
#pragma unroll
        for (int jj = 0; jj < 4; ++jj) acc[i][jj] = fmaf(a[i], b[jj], acc[i][jj]);
    }
    __syncthreads();
  }
  float4 a4 = *reinterpret_cast<const float4*>(&A[bn + tx * 4]);
  float4 b4 = *reinterpret_cast<const float4*>(&B[bn + tx * 4]);
  float as[4] = {a4.x, a4.y, a4.z, a4.w};
  float bsv[4] = {b4.x, b4.y, b4.z, b4.w};
#pragma unroll
  for (int i = 0; i < 4; ++i) {
    int row = bm + ty * 4 + i;
    if (row < M) {
      float4 ov;
      ov.x = fmaxf(fmaf(acc[i][0], as[0], bsv[0]), 0.f);
      ov.y = fmaxf(fmaf(acc[i][1], as[1], bsv[1]), 0.f);
      ov.z = fmaxf(fmaf(acc[i][2], as[2], bsv[2]), 0.f);
      ov.w = fmaxf(fmaf(acc[i][3], as[3], bsv[3]), 0.f);
      *reinterpret_cast<float4*>(&Y[(size_t)row * HDIM + bn + tx * 4]) = ov;
    }
  }
}

// ---------- pooling ----------

__global__ void k_goff(const int* __restrict__ batch, int* __restrict__ goff, int G, int n) {
  int g = blockIdx.x * 256 + threadIdx.x;
  if (g > G) return;
  int lo = 0, hi = n;
  while (lo < hi) {
    int mid = (lo + hi) >> 1;
    if (batch[mid] < g) lo = mid + 1;
    else hi = mid;
  }
  goff[g] = lo;
}

__global__ __launch_bounds__(256) void k_pool(
    const float* __restrict__ X, const int* __restrict__ goff,
    float* __restrict__ P, int G) {
  int g = blockIdx.x * 4 + (threadIdx.x >> 6);
  if (g >= G) return;
  int j = (threadIdx.x & 63) * 4;
  int r0 = goff[g], r1 = goff[g + 1];
  float4 acc = make_float4(0.f, 0.f, 0.f, 0.f);
  for (int r = r0; r < r1; ++r) {
    float4 x4 = *reinterpret_cast<const float4*>(&X[(size_t)r * HDIM + j]);
    acc.x += x4.x; acc.y += x4.y; acc.z += x4.z; acc.w += x4.w;
  }
  float inv = 1.f / fmaxf((float)(r1 - r0), 1.f);
  float4 o = make_float4(acc.x * inv, acc.y * inv, acc.z * inv, acc.w * inv);
  *reinterpret_cast<float4*>(&P[(size_t)g * HDIM + j]) = o;
}

// ---------- final projection: out[g] = pooled[g] @ projW + projb ----------

__global__ __launch_bounds__(128) void k_proj(
    const float* __restrict__ P, const float* __restrict__ W,
    const float* __restrict__ bias, float* __restrict__ out, int G) {
  __shared__ float rows[8][HDIM];
  int g0 = blockIdx.x * 8;
  for (int i = threadIdx.x; i < 8 * HDIM; i += 128) {
    int g = g0 + (i >> 8);
    rows[i >> 8][i & 255] = (g < G) ? P[(size_t)g * HDIM + (i & 255)] : 0.f;
  }
  __syncthreads();
  int d = threadIdx.x;
  float bb = bias[d];
  float acc[8] = {bb, bb, bb, bb, bb, bb, bb, bb};
  for (int k = 0; k < HDIM; ++k) {
    float w = W[(size_t)k * DDIM + d];
#pragma unroll
    for (int q = 0; q < 8; ++q) acc[q] = fmaf(rows[q][k], w, acc[q]);
  }
#pragma unroll
  for (int q = 0; q < 8; ++q) {
    int g = g0 + q;
    if (g < G) out[(size_t)g * DDIM + d] = acc[q];
  }
}

// ---------- launch ----------

extern "C" void kernel_launch(void* const* d_in, const int* in_sizes, int n_in,
                              void* d_out, int out_size, void* d_ws, size_t ws_size,
                              hipStream_t stream) {
  const int N = in_sizes[0];
  const int E = in_sizes[1] / 2;
  const int G = out_size / DDIM;

  const int* node_ids = (const int*)d_in[0];
  const int* src = (const int*)d_in[1];
  const int* dst = src + E;
  const int* batch = (const int*)d_in[2];
  const float* emb = (const float*)d_in[3];
  const float* Ws = (const float*)d_in[4];
  const float* bs = (const float*)d_in[5];
  const float* gam = (const float*)d_in[6];
  const float* bet = (const float*)d_in[7];
  const float* mu = (const float*)d_in[8];
  const float* va = (const float*)d_in[9];
  const float* pW = (const float*)d_in[10];
  const float* pb = (const float*)d_in[11];
  float* out = (float*)d_out;

  size_t o = 0;
  auto alloc = [&](size_t bytes) -> void* {
    size_t start = (o + 255) & ~(size_t)255;
    o = start + bytes;
    return (void*)((char*)d_ws + start);
  };
  int NB = (N + 255) / 256;
  int* cnt = (int*)alloc((size_t)N * 4);
  float* dinv = (float*)alloc((size_t)N * 4);
  int* off = (int*)alloc((size_t)(N + 1) * 4);
  int* bsum = (int*)alloc((size_t)NB * 4);
  int* csr_src = (int*)alloc((size_t)E * 4);
  float* csr_w = (float*)alloc((size_t)E * 4);
  int* csr_id = (int*)alloc((size_t)E * 4);
  float* embW = (float*)alloc((size_t)VSZ * HDIM * 4);
  float* Ac = (float*)alloc((size_t)3 * HDIM * 4);
  float* Bc = (float*)alloc((size_t)3 * HDIM * 4);
  int* goff = (int*)alloc((size_t)(G + 1) * 4);
  float* bufA = (float*)alloc((size_t)N * HDIM * 4);
  float* bufB = (float*)alloc((size_t)N * HDIM * 4);
  float* pooled = (float*)alloc((size_t)G * HDIM * 4);

  int gE = (E + 255) / 256;
  int gN = (N + 255) / 256;

  // CSR build
  hipMemsetAsync(cnt, 0, (size_t)N * 4, stream);
  k_count<<<gE, 256, 0, stream>>>(dst, cnt, E);
  k_dinv<<<gN, 256, 0, stream>>>(cnt, dinv, N);
  k_scan_chunk<<<NB, 256, 0, stream>>>(cnt, off, bsum, N);
  k_scan_bsum<<<1, 64, 0, stream>>>(bsum, NB);
  k_scan_add<<<(N + 1 + 255) / 256, 256, 0, stream>>>(off, bsum, N, E);
  hipMemsetAsync(cnt, 0, (size_t)N * 4, stream);
  k_fill<<<gE, 256, 0, stream>>>(src, dst, node_ids, dinv, off, cnt,
                                 csr_src, csr_w, csr_id, E);

  // tiny precomputes
  k_embw<<<VSZ, HDIM, 0, stream>>>(emb, Ws, embW);
  k_bnc<<<3, HDIM, 0, stream>>>(bs, gam, bet, mu, va, Ac, Bc);

  // layer 1 (fused: aggregate 14-row table + BN + ReLU)
  k_layer1<<<(N + 3) / 4, 256, 0, stream>>>(node_ids, embW, off, csr_id, csr_w,
                                            dinv, Ac, Bc, bufA, N);

  // layers 2,3: aggregate then GEMM+BN+ReLU
  dim3 gg((N + 63) / 64, 4);
  k_agg<<<(N + 3) / 4, 256, 0, stream>>>(bufA, off, csr_src, csr_w, dinv, bufB, N);
  k_gemm<<<gg, 256, 0, stream>>>(bufB, Ws + 1 * HDIM * HDIM, Ac + HDIM, Bc + HDIM, bufA, N);
  k_agg<<<(N + 3) / 4, 256, 0, stream>>>(bufA, off, csr_src, csr_w, dinv, bufB, N);
  k_gemm<<<gg, 256, 0, stream>>>(bufB, Ws + 2 * HDIM * HDIM, Ac + 2 * HDIM, Bc + 2 * HDIM, bufA, N);

  // pooling + projection
  k_goff<<<(G + 1 + 255) / 256, 256, 0, stream>>>(batch, goff, G, N);
  k_pool<<<(G + 3) / 4, 256, 0, stream>>>(bufA, goff, pooled, G);
  k_proj<<<(G + 7) / 8, 128, 0, stream>>>(pooled, pW, pb, out, G);
}

// Round 2
// 455.754 us; speedup vs baseline: 1.5644x; 1.5644x over previous
//
#include <hip/hip_runtime.h>

#define HDIM 256
#define DDIM 128
#define VSZ 14

typedef __bf16 bf16x8 __attribute__((ext_vector_type(8)));
typedef float f32x4 __attribute__((ext_vector_type(4)));

static __device__ __forceinline__ unsigned short f2bf(float f) {
  unsigned u = __builtin_bit_cast(unsigned, f);
  u += 0x7FFF + ((u >> 16) & 1);  // round-to-nearest-even
  return (unsigned short)(u >> 16);
}

// ---------- degree / CSR construction ----------

__global__ void k_count(const int* __restrict__ dst, int* __restrict__ cnt, int E) {
  int i = blockIdx.x * 256 + threadIdx.x;
  if (i < E) atomicAdd(&cnt[dst[i]], 1);
}

__global__ void k_dinv(const int* __restrict__ cnt, float* __restrict__ dinv, int n) {
  int i = blockIdx.x * 256 + threadIdx.x;
  if (i < n) dinv[i] = rsqrtf((float)(cnt[i] + 1));  // +1 self-loop
}

__global__ void k_scan_chunk(const int* __restrict__ cnt, int* __restrict__ off,
                             int* __restrict__ bsum, int n) {
  __shared__ int s[256];
  int i = blockIdx.x * 256 + threadIdx.x;
  int v = (i < n) ? cnt[i] : 0;
  s[threadIdx.x] = v;
  __syncthreads();
  for (int d = 1; d < 256; d <<= 1) {
    int add = (threadIdx.x >= d) ? s[threadIdx.x - d] : 0;
    __syncthreads();
    s[threadIdx.x] += add;
    __syncthreads();
  }
  if (i < n) off[i] = s[threadIdx.x] - v;
  if (threadIdx.x == 255) bsum[blockIdx.x] = s[255];
}

__global__ void k_scan_bsum(int* bsum, int nb) {
  if (threadIdx.x == 0) {
    int acc = 0;
    for (int b = 0; b < nb; ++b) { int t = bsum[b]; bsum[b] = acc; acc += t; }
  }
}

__global__ void k_scan_add(int* __restrict__ off, const int* __restrict__ bsum, int n, int E) {
  int i = blockIdx.x * 256 + threadIdx.x;
  if (i < n) off[i] += bsum[i >> 8];
  else if (i == n) off[n] = E;
}

__global__ void k_fill(const int* __restrict__ src, const int* __restrict__ dst,
                       const int* __restrict__ ids, const float* __restrict__ dinv,
                       const int* __restrict__ off, int* __restrict__ cur,
                       int* __restrict__ csr_src, float* __restrict__ csr_w,
                       int* __restrict__ csr_id, int E) {
  int i = blockIdx.x * 256 + threadIdx.x;
  if (i >= E) return;
  int d = dst[i];
  int p = off[d] + atomicAdd(&cur[d], 1);
  int s = src[i];
  csr_src[p] = s;
  csr_w[p] = dinv[s];
  csr_id[p] = ids[s];
}

// ---------- tiny precomputes ----------

__global__ void k_embw(const float* __restrict__ emb, const float* __restrict__ W0,
                       float* __restrict__ embW) {
  int t = blockIdx.x, j = threadIdx.x;
  float acc = 0.f;
  for (int k = 0; k < HDIM; ++k) acc = fmaf(emb[t * HDIM + k], W0[k * HDIM + j], acc);
  embW[t * HDIM + j] = acc;
}

__global__ void k_bnc(const float* __restrict__ bs, const float* __restrict__ g,
                      const float* __restrict__ be, const float* __restrict__ mu,
                      const float* __restrict__ va, float* __restrict__ A,
                      float* __restrict__ B) {
  int i = blockIdx.x * HDIM + threadIdx.x;
  float a = g[i] * rsqrtf(va[i] + 1e-5f);
  A[i] = a;
  B[i] = (bs[i] - mu[i]) * a + be[i];
}

// transpose + convert W (256x256 f32, k-major) -> Wt (256x256 bf16, n-major: Wt[n][k])
__global__ __launch_bounds__(256) void k_wcvt(const float* __restrict__ W,
                                              unsigned short* __restrict__ Wt) {
  __shared__ float tile[32][33];
  int bx = blockIdx.x * 32, by = blockIdx.y * 32;
  int tx = threadIdx.x & 31, ty = threadIdx.x >> 5;  // 32 x 8
#pragma unroll
  for (int i = 0; i < 4; ++i)
    tile[ty + i * 8][tx] = W[(size_t)(by + ty + i * 8) * HDIM + bx + tx];
  __syncthreads();
#pragma unroll
  for (int i = 0; i < 4; ++i)
    Wt[(size_t)(bx + ty + i * 8) * HDIM + by + tx] = f2bf(tile[tx][ty + i * 8]);
}

// ---------- layer 1 fused: aggregate embW rows + BN + ReLU (fp32 out) ----------

__global__ __launch_bounds__(256) void k_layer1(
    const int* __restrict__ ids, const float* __restrict__ embW,
    const int* __restrict__ off, const int* __restrict__ csr_id,
    const float* __restrict__ csr_w, const float* __restrict__ dinv,
    const float* __restrict__ A, const float* __restrict__ B,
    float* __restrict__ Y, int n) {
  __shared__ float lw[VSZ * HDIM];
  for (int i = threadIdx.x; i < VSZ * HDIM; i += 256) lw[i] = embW[i];
  __syncthreads();
  int v = blockIdx.x * 4 + (threadIdx.x >> 6);
  if (v >= n) return;
  int j = (threadIdx.x & 63) * 4;
  float dv = dinv[v];
  float s = dv * dv;
  float4 e4 = *reinterpret_cast<const float4*>(&lw[ids[v] * HDIM + j]);
  float4 acc = make_float4(s * e4.x, s * e4.y, s * e4.z, s * e4.w);
  int e1 = off[v + 1];
  for (int e = off[v]; e < e1; ++e) {
    float w = dv * csr_w[e];
    float4 m = *reinterpret_cast<const float4*>(&lw[csr_id[e] * HDIM + j]);
    acc.x = fmaf(w, m.x, acc.x);
    acc.y = fmaf(w, m.y, acc.y);
    acc.z = fmaf(w, m.z, acc.z);
    acc.w = fmaf(w, m.w, acc.w);
  }
  float4 a4 = *reinterpret_cast<const float4*>(&A[j]);
  float4 b4 = *reinterpret_cast<const float4*>(&B[j]);
  float4 o;
  o.x = fmaxf(fmaf(acc.x, a4.x, b4.x), 0.f);
  o.y = fmaxf(fmaf(acc.y, a4.y, b4.y), 0.f);
  o.z = fmaxf(fmaf(acc.z, a4.z, b4.z), 0.f);
  o.w = fmaxf(fmaf(acc.w, a4.w, b4.w), 0.f);
  *reinterpret_cast<float4*>(&Y[(size_t)v * HDIM + j]) = o;
}

// ---------- aggregation (fp32 gather, bf16 out for MFMA GEMM) ----------

__global__ __launch_bounds__(256) void k_agg(
    const float* __restrict__ X, const int* __restrict__ off,
    const int* __restrict__ csr_src, const float* __restrict__ csr_w,
    const float* __restrict__ dinv, unsigned short* __restrict__ Yb, int n) {
  int v = blockIdx.x * 4 + (threadIdx.x >> 6);
  if (v >= n) return;
  int j = (threadIdx.x & 63) * 4;
  float dv = dinv[v];
  float s = dv * dv;
  float4 x4 = *reinterpret_cast<const float4*>(&X[(size_t)v * HDIM + j]);
  float4 acc = make_float4(s * x4.x, s * x4.y, s * x4.z, s * x4.w);
  int e1 = off[v + 1];
  for (int e = off[v]; e < e1; ++e) {
    float w = dv * csr_w[e];
    float4 m = *reinterpret_cast<const float4*>(&X[(size_t)csr_src[e] * HDIM + j]);
    acc.x = fmaf(w, m.x, acc.x);
    acc.y = fmaf(w, m.y, acc.y);
    acc.z = fmaf(w, m.z, acc.z);
    acc.w = fmaf(w, m.w, acc.w);
  }
  ushort4 o;
  o.x = f2bf(acc.x); o.y = f2bf(acc.y); o.z = f2bf(acc.z); o.w = f2bf(acc.w);
  *reinterpret_cast<ushort4*>(&Yb[(size_t)v * HDIM + j]) = o;
}

// ---------- bf16 MFMA GEMM (M x 256) @ (256 x 256) + BN + ReLU ----------
// Xb: M x 256 bf16 row-major; Wt: 256(n) x 256(k) bf16 (W transposed)

#define BM 128
#define BN 128
#define BK 32
#define LDK 40  // padded LDS row stride (elements); 80B -> 2-way bank aliasing (free)

__global__ __launch_bounds__(256) void k_gemm_mfma(
    const unsigned short* __restrict__ Xb, const unsigned short* __restrict__ Wt,
    const float* __restrict__ Asc, const float* __restrict__ Bsh,
    float* __restrict__ Y, int M) {
  __shared__ unsigned short As[BM * LDK];
  __shared__ unsigned short Bs[BN * LDK];
  int t = threadIdx.x;
  int m0 = blockIdx.x * BM;
  int n0 = blockIdx.y * BN;
  int l = t & 63, w = t >> 6;
  int wm = w & 1, wn = w >> 1;      // 2x2 wave grid, each wave 64x64
  int cl = l & 15, q = l >> 4;
  int r0 = t >> 2;                  // 0..63 staging row
  int kc = (t & 3) * 8;             // staging k-offset (elements)

  f32x4 acc[4][4];
  f32x4 zf = {0.f, 0.f, 0.f, 0.f};
#pragma unroll
  for (int i = 0; i < 4; ++i)
#pragma unroll
    for (int jj = 0; jj < 4; ++jj) acc[i][jj] = zf;

  int arow0 = m0 + r0;      if (arow0 > M - 1) arow0 = M - 1;
  int arow1 = m0 + r0 + 64; if (arow1 > M - 1) arow1 = M - 1;
  int brow0 = n0 + r0, brow1 = n0 + r0 + 64;

  for (int k0 = 0; k0 < HDIM; k0 += BK) {
    uint4 a0 = *reinterpret_cast<const uint4*>(&Xb[(size_t)arow0 * HDIM + k0 + kc]);
    uint4 a1 = *reinterpret_cast<const uint4*>(&Xb[(size_t)arow1 * HDIM + k0 + kc]);
    uint4 b0 = *reinterpret_cast<const uint4*>(&Wt[(size_t)brow0 * HDIM + k0 + kc]);
    uint4 b1 = *reinterpret_cast<const uint4*>(&Wt[(size_t)brow1 * HDIM + k0 + kc]);
    __syncthreads();  // previous iteration's reads done
    *reinterpret_cast<uint4*>(&As[r0 * LDK + kc]) = a0;
    *reinterpret_cast<uint4*>(&As[(r0 + 64) * LDK + kc]) = a1;
    *reinterpret_cast<uint4*>(&Bs[r0 * LDK + kc]) = b0;
    *reinterpret_cast<uint4*>(&Bs[(r0 + 64) * LDK + kc]) = b1;
    __syncthreads();
    bf16x8 af[4], bf[4];
#pragma unroll
    for (int i = 0; i < 4; ++i)
      af[i] = *reinterpret_cast<const bf16x8*>(&As[(wm * 64 + i * 16 + cl) * LDK + q * 8]);
#pragma unroll
    for (int jj = 0; jj < 4; ++jj)
      bf[jj] = *reinterpret_cast<const bf16x8*>(&Bs[(wn * 64 + jj * 16 + cl) * LDK + q * 8]);
#pragma unroll
    for (int i = 0; i < 4; ++i)
#pragma unroll
      for (int jj = 0; jj < 4; ++jj)
        acc[i][jj] = __builtin_amdgcn_mfma_f32_16x16x32_bf16(af[i], bf[jj], acc[i][jj], 0, 0, 0);
  }

  // epilogue: D row = q*4 + r (within 16), col = cl; fused BN + ReLU
#pragma unroll
  for (int jj = 0; jj < 4; ++jj) {
    int col = n0 + wn * 64 + jj * 16 + cl;
    float as = Asc[col], bsv = Bsh[col];
#pragma unroll
    for (int i = 0; i < 4; ++i) {
      int rowb = m0 + wm * 64 + i * 16 + q * 4;
#pragma unroll
      for (int r = 0; r < 4; ++r) {
        int row = rowb + r;
        if (row < M) Y[(size_t)row * HDIM + col] = fmaxf(fmaf(acc[i][jj][r], as, bsv), 0.f);
      }
    }
  }
}

// ---------- pooling ----------

__global__ void k_goff(const int* __restrict__ batch, int* __restrict__ goff, int G, int n) {
  int g = blockIdx.x * 256 + threadIdx.x;
  if (g > G) return;
  int lo = 0, hi = n;
  while (lo < hi) {
    int mid = (lo + hi) >> 1;
    if (batch[mid] < g) lo = mid + 1;
    else hi = mid;
  }
  goff[g] = lo;
}

__global__ __launch_bounds__(256) void k_pool(
    const float* __restrict__ X, const int* __restrict__ goff,
    float* __restrict__ P, int G) {
  int g = blockIdx.x * 4 + (threadIdx.x >> 6);
  if (g >= G) return;
  int j = (threadIdx.x & 63) * 4;
  int r0 = goff[g], r1 = goff[g + 1];
  float4 acc = make_float4(0.f, 0.f, 0.f, 0.f);
  for (int r = r0; r < r1; ++r) {
    float4 x4 = *reinterpret_cast<const float4*>(&X[(size_t)r * HDIM + j]);
    acc.x += x4.x; acc.y += x4.y; acc.z += x4.z; acc.w += x4.w;
  }
  float inv = 1.f / fmaxf((float)(r1 - r0), 1.f);
  float4 o = make_float4(acc.x * inv, acc.y * inv, acc.z * inv, acc.w * inv);
  *reinterpret_cast<float4*>(&P[(size_t)g * HDIM + j]) = o;
}

// ---------- final projection ----------

__global__ __launch_bounds__(128) void k_proj(
    const float* __restrict__ P, const float* __restrict__ W,
    const float* __restrict__ bias, float* __restrict__ out, int G) {
  __shared__ float rows[8][HDIM];
  int g0 = blockIdx.x * 8;
  for (int i = threadIdx.x; i < 8 * HDIM; i += 128) {
    int g = g0 + (i >> 8);
    rows[i >> 8][i & 255] = (g < G) ? P[(size_t)g * HDIM + (i & 255)] : 0.f;
  }
  __syncthreads();
  int d = threadIdx.x;
  float bb = bias[d];
  float acc[8] = {bb, bb, bb, bb, bb, bb, bb, bb};
  for (int k = 0; k < HDIM; ++k) {
    float w = W[(size_t)k * DDIM + d];
#pragma unroll
    for (int q = 0; q < 8; ++q) acc[q] = fmaf(rows[q][k], w, acc[q]);
  }
#pragma unroll
  for (int q = 0; q < 8; ++q) {
    int g = g0 + q;
    if (g < G) out[(size_t)g * DDIM + d] = acc[q];
  }
}

// ---------- launch ----------

extern "C" void kernel_launch(void* const* d_in, const int* in_sizes, int n_in,
                              void* d_out, int out_size, void* d_ws, size_t ws_size,
                              hipStream_t stream) {
  const int N = in_sizes[0];
  const int E = in_sizes[1] / 2;
  const int G = out_size / DDIM;

  const int* node_ids = (const int*)d_in[0];
  const int* src = (const int*)d_in[1];
  const int* dst = src + E;
  const int* batch = (const int*)d_in[2];
  const float* emb = (const float*)d_in[3];
  const float* Ws = (const float*)d_in[4];
  const float* bs = (const float*)d_in[5];
  const float* gam = (const float*)d_in[6];
  const float* bet = (const float*)d_in[7];
  const float* mu = (const float*)d_in[8];
  const float* va = (const float*)d_in[9];
  const float* pW = (const float*)d_in[10];
  const float* pb = (const float*)d_in[11];
  float* out = (float*)d_out;

  size_t o = 0;
  auto alloc = [&](size_t bytes) -> void* {
    size_t start = (o + 255) & ~(size_t)255;
    o = start + bytes;
    return (void*)((char*)d_ws + start);
  };
  int NB = (N + 255) / 256;
  int* cnt = (int*)alloc((size_t)N * 4);
  float* dinv = (float*)alloc((size_t)N * 4);
  int* off = (int*)alloc((size_t)(N + 1) * 4);
  int* bsum = (int*)alloc((size_t)NB * 4);
  int* csr_src = (int*)alloc((size_t)E * 4);
  float* csr_w = (float*)alloc((size_t)E * 4);
  int* csr_id = (int*)alloc((size_t)E * 4);
  float* embW = (float*)alloc((size_t)VSZ * HDIM * 4);
  float* Ac = (float*)alloc((size_t)3 * HDIM * 4);
  float* Bc = (float*)alloc((size_t)3 * HDIM * 4);
  int* goff = (int*)alloc((size_t)(G + 1) * 4);
  unsigned short* Wtb = (unsigned short*)alloc((size_t)2 * HDIM * HDIM * 2);
  float* bufA = (float*)alloc((size_t)N * HDIM * 4);          // fp32 node features
  unsigned short* Xb = (unsigned short*)alloc((size_t)N * HDIM * 2);  // bf16 GEMM input
  float* pooled = (float*)alloc((size_t)G * HDIM * 4);

  int gE = (E + 255) / 256;
  int gN = (N + 255) / 256;

  // CSR build
  hipMemsetAsync(cnt, 0, (size_t)N * 4, stream);
  k_count<<<gE, 256, 0, stream>>>(dst, cnt, E);
  k_dinv<<<gN, 256, 0, stream>>>(cnt, dinv, N);
  k_scan_chunk<<<NB, 256, 0, stream>>>(cnt, off, bsum, N);
  k_scan_bsum<<<1, 64, 0, stream>>>(bsum, NB);
  k_scan_add<<<(N + 1 + 255) / 256, 256, 0, stream>>>(off, bsum, N, E);
  hipMemsetAsync(cnt, 0, (size_t)N * 4, stream);
  k_fill<<<gE, 256, 0, stream>>>(src, dst, node_ids, dinv, off, cnt,
                                 csr_src, csr_w, csr_id, E);

  // tiny precomputes
  k_embw<<<VSZ, HDIM, 0, stream>>>(emb, Ws, embW);
  k_bnc<<<3, HDIM, 0, stream>>>(bs, gam, bet, mu, va, Ac, Bc);
  dim3 tg(8, 8);
  k_wcvt<<<tg, 256, 0, stream>>>(Ws + 1 * HDIM * HDIM, Wtb);
  k_wcvt<<<tg, 256, 0, stream>>>(Ws + 2 * HDIM * HDIM, Wtb + HDIM * HDIM);

  // layer 1 (fused: aggregate 14-row table + BN + ReLU)
  k_layer1<<<(N + 3) / 4, 256, 0, stream>>>(node_ids, embW, off, csr_id, csr_w,
                                            dinv, Ac, Bc, bufA, N);

  // layers 2,3: aggregate (fp32 -> bf16) then MFMA GEMM + BN + ReLU (-> fp32)
  dim3 gg((N + BM - 1) / BM, HDIM / BN);
  k_agg<<<(N + 3) / 4, 256, 0, stream>>>(bufA, off, csr_src, csr_w, dinv, Xb, N);
  k_gemm_mfma<<<gg, 256, 0, stream>>>(Xb, Wtb, Ac + HDIM, Bc + HDIM, bufA, N);
  k_agg<<<(N + 3) / 4, 256, 0, stream>>>(bufA, off, csr_src, csr_w, dinv, Xb, N);
  k_gemm_mfma<<<gg, 256, 0, stream>>>(Xb, Wtb + HDIM * HDIM, Ac + 2 * HDIM, Bc + 2 * HDIM, bufA, N);

  // pooling + projection
  k_goff<<<(G + 1 + 255) / 256, 256, 0, stream>>>(batch, goff, G, N);
  k_pool<<<(G + 3) / 4, 256, 0, stream>>>(bufA, goff, pooled, G);
  k_proj<<<(G + 7) / 8, 128, 0, stream>>>(pooled, pW, pb, out, G);
}

// Round 3
// 390.738 us; speedup vs baseline: 1.8247x; 1.1664x over previous
//
#include <hip/hip_runtime.h>

#define HDIM 256
#define DDIM 128
#define VSZ 14

typedef __bf16 bf16x8 __attribute__((ext_vector_type(8)));
typedef float f32x4 __attribute__((ext_vector_type(4)));

static __device__ __forceinline__ unsigned short f2bf(float f) {
  unsigned u = __builtin_bit_cast(unsigned, f);
  u += 0x7FFF + ((u >> 16) & 1);  // round-to-nearest-even
  return (unsigned short)(u >> 16);
}
static __device__ __forceinline__ float bf2f(unsigned short u) {
  unsigned x = ((unsigned)u) << 16;
  return __builtin_bit_cast(float, x);
}

// ---------- degree / CSR construction ----------

__global__ void k_count(const int* __restrict__ dst, int* __restrict__ cnt, int E) {
  int i = blockIdx.x * 256 + threadIdx.x;
  if (i < E) atomicAdd(&cnt[dst[i]], 1);
}

__global__ void k_dinv(const int* __restrict__ cnt, float* __restrict__ dinv, int n) {
  int i = blockIdx.x * 256 + threadIdx.x;
  if (i < n) dinv[i] = rsqrtf((float)(cnt[i] + 1));  // +1 self-loop
}

__global__ void k_scan_chunk(const int* __restrict__ cnt, int* __restrict__ off,
                             int* __restrict__ bsum, int n) {
  __shared__ int s[256];
  int i = blockIdx.x * 256 + threadIdx.x;
  int v = (i < n) ? cnt[i] : 0;
  s[threadIdx.x] = v;
  __syncthreads();
  for (int d = 1; d < 256; d <<= 1) {
    int add = (threadIdx.x >= d) ? s[threadIdx.x - d] : 0;
    __syncthreads();
    s[threadIdx.x] += add;
    __syncthreads();
  }
  if (i < n) off[i] = s[threadIdx.x] - v;
  if (threadIdx.x == 255) bsum[blockIdx.x] = s[255];
}

__global__ void k_scan_bsum(int* bsum, int nb) {
  if (threadIdx.x == 0) {
    int acc = 0;
    for (int b = 0; b < nb; ++b) { int t = bsum[b]; bsum[b] = acc; acc += t; }
  }
}

__global__ void k_scan_add(int* __restrict__ off, const int* __restrict__ bsum, int n, int E) {
  int i = blockIdx.x * 256 + threadIdx.x;
  if (i < n) off[i] += bsum[i >> 8];
  else if (i == n) off[n] = E;
}

// packed edge record: {src, id(src), dinv(src) bits, 0}
__global__ void k_fill(const int* __restrict__ src, const int* __restrict__ dst,
                       const int* __restrict__ ids, const float* __restrict__ dinv,
                       const int* __restrict__ off, int* __restrict__ cur,
                       int4* __restrict__ edata, int E) {
  int i = blockIdx.x * 256 + threadIdx.x;
  if (i >= E) return;
  int d = dst[i];
  int p = off[d] + atomicAdd(&cur[d], 1);
  int s = src[i];
  int4 v;
  v.x = s;
  v.y = ids[s];
  v.z = __builtin_bit_cast(int, dinv[s]);
  v.w = 0;
  edata[p] = v;
}

// ---------- tiny precomputes ----------

__global__ void k_embw(const float* __restrict__ emb, const float* __restrict__ W0,
                       float* __restrict__ embW) {
  int t = blockIdx.x, j = threadIdx.x;
  float acc = 0.f;
  for (int k = 0; k < HDIM; ++k) acc = fmaf(emb[t * HDIM + k], W0[k * HDIM + j], acc);
  embW[t * HDIM + j] = acc;
}

__global__ void k_bnc(const float* __restrict__ bs, const float* __restrict__ g,
                      const float* __restrict__ be, const float* __restrict__ mu,
                      const float* __restrict__ va, float* __restrict__ A,
                      float* __restrict__ B) {
  int i = blockIdx.x * HDIM + threadIdx.x;
  float a = g[i] * rsqrtf(va[i] + 1e-5f);
  A[i] = a;
  B[i] = (bs[i] - mu[i]) * a + be[i];
}

// transpose + convert W (256x256 f32, k-major) -> Wt (256x256 bf16, n-major)
__global__ __launch_bounds__(256) void k_wcvt(const float* __restrict__ W,
                                              unsigned short* __restrict__ Wt) {
  __shared__ float tile[32][33];
  int bx = blockIdx.x * 32, by = blockIdx.y * 32;
  int tx = threadIdx.x & 31, ty = threadIdx.x >> 5;
#pragma unroll
  for (int i = 0; i < 4; ++i)
    tile[ty + i * 8][tx] = W[(size_t)(by + ty + i * 8) * HDIM + bx + tx];
  __syncthreads();
#pragma unroll
  for (int i = 0; i < 4; ++i)
    Wt[(size_t)(bx + ty + i * 8) * HDIM + by + tx] = f2bf(tile[tx][ty + i * 8]);
}

// ---------- layer 1: aggregate 14-row table + BN + ReLU -> bf16 ----------

__global__ __launch_bounds__(256) void k_layer1(
    const int* __restrict__ ids, const float* __restrict__ embW,
    const int* __restrict__ off, const int4* __restrict__ edata,
    const float* __restrict__ dinv,
    const float* __restrict__ A, const float* __restrict__ B,
    unsigned short* __restrict__ Y, int n) {
  __shared__ float lw[VSZ * HDIM];
  for (int i = threadIdx.x; i < VSZ * HDIM; i += 256) lw[i] = embW[i];
  __syncthreads();
  int v = blockIdx.x * 4 + (threadIdx.x >> 6);
  if (v >= n) return;
  int j = (threadIdx.x & 63) * 4;
  float dv = dinv[v];
  float s = dv * dv;
  float4 e4 = *reinterpret_cast<const float4*>(&lw[ids[v] * HDIM + j]);
  float4 acc = make_float4(s * e4.x, s * e4.y, s * e4.z, s * e4.w);
  int e = off[v], e1 = off[v + 1];
  for (; e + 1 < e1; e += 2) {
    int4 d0 = edata[e];
    int4 d1 = edata[e + 1];
    float w0 = dv * __builtin_bit_cast(float, d0.z);
    float w1 = dv * __builtin_bit_cast(float, d1.z);
    float4 m0 = *reinterpret_cast<const float4*>(&lw[d0.y * HDIM + j]);
    float4 m1 = *reinterpret_cast<const float4*>(&lw[d1.y * HDIM + j]);
    acc.x = fmaf(w0, m0.x, fmaf(w1, m1.x, acc.x));
    acc.y = fmaf(w0, m0.y, fmaf(w1, m1.y, acc.y));
    acc.z = fmaf(w0, m0.z, fmaf(w1, m1.z, acc.z));
    acc.w = fmaf(w0, m0.w, fmaf(w1, m1.w, acc.w));
  }
  if (e < e1) {
    int4 d0 = edata[e];
    float w0 = dv * __builtin_bit_cast(float, d0.z);
    float4 m0 = *reinterpret_cast<const float4*>(&lw[d0.y * HDIM + j]);
    acc.x = fmaf(w0, m0.x, acc.x);
    acc.y = fmaf(w0, m0.y, acc.y);
    acc.z = fmaf(w0, m0.z, acc.z);
    acc.w = fmaf(w0, m0.w, acc.w);
  }
  float4 a4 = *reinterpret_cast<const float4*>(&A[j]);
  float4 b4 = *reinterpret_cast<const float4*>(&B[j]);
  ushort4 o;
  o.x = f2bf(fmaxf(fmaf(acc.x, a4.x, b4.x), 0.f));
  o.y = f2bf(fmaxf(fmaf(acc.y, a4.y, b4.y), 0.f));
  o.z = f2bf(fmaxf(fmaf(acc.z, a4.z, b4.z), 0.f));
  o.w = f2bf(fmaxf(fmaf(acc.w, a4.w, b4.w), 0.f));
  *reinterpret_cast<ushort4*>(&Y[(size_t)v * HDIM + j]) = o;
}

// ---------- aggregation: bf16 gather -> bf16 out ----------

__global__ __launch_bounds__(256) void k_agg(
    const unsigned short* __restrict__ X, const int* __restrict__ off,
    const int4* __restrict__ edata, const float* __restrict__ dinv,
    unsigned short* __restrict__ Yb, int n) {
  int v = blockIdx.x * 4 + (threadIdx.x >> 6);
  if (v >= n) return;
  int j = (threadIdx.x & 63) * 4;
  float dv = dinv[v];
  float s = dv * dv;
  ushort4 x4 = *reinterpret_cast<const ushort4*>(&X[(size_t)v * HDIM + j]);
  float4 acc = make_float4(s * bf2f(x4.x), s * bf2f(x4.y), s * bf2f(x4.z), s * bf2f(x4.w));
  int e = off[v], e1 = off[v + 1];
  for (; e + 1 < e1; e += 2) {
    int4 d0 = edata[e];
    int4 d1 = edata[e + 1];
    float w0 = dv * __builtin_bit_cast(float, d0.z);
    float w1 = dv * __builtin_bit_cast(float, d1.z);
    ushort4 m0 = *reinterpret_cast<const ushort4*>(&X[(size_t)d0.x * HDIM + j]);
    ushort4 m1 = *reinterpret_cast<const ushort4*>(&X[(size_t)d1.x * HDIM + j]);
    acc.x = fmaf(w0, bf2f(m0.x), fmaf(w1, bf2f(m1.x), acc.x));
    acc.y = fmaf(w0, bf2f(m0.y), fmaf(w1, bf2f(m1.y), acc.y));
    acc.z = fmaf(w0, bf2f(m0.z), fmaf(w1, bf2f(m1.z), acc.z));
    acc.w = fmaf(w0, bf2f(m0.w), fmaf(w1, bf2f(m1.w), acc.w));
  }
  if (e < e1) {
    int4 d0 = edata[e];
    float w0 = dv * __builtin_bit_cast(float, d0.z);
    ushort4 m0 = *reinterpret_cast<const ushort4*>(&X[(size_t)d0.x * HDIM + j]);
    acc.x = fmaf(w0, bf2f(m0.x), acc.x);
    acc.y = fmaf(w0, bf2f(m0.y), acc.y);
    acc.z = fmaf(w0, bf2f(m0.z), acc.z);
    acc.w = fmaf(w0, bf2f(m0.w), acc.w);
  }
  ushort4 o;
  o.x = f2bf(acc.x); o.y = f2bf(acc.y); o.z = f2bf(acc.z); o.w = f2bf(acc.w);
  *reinterpret_cast<ushort4*>(&Yb[(size_t)v * HDIM + j]) = o;
}

// ---------- bf16 MFMA GEMM (M x 256) @ (256 x 256) + BN + ReLU -> bf16 ----------

#define BM 128
#define BN 128
#define BK 32
#define LDK 40  // padded LDS row stride (elements)

__global__ __launch_bounds__(256) void k_gemm_mfma(
    const unsigned short* __restrict__ Xb, const unsigned short* __restrict__ Wt,
    const float* __restrict__ Asc, const float* __restrict__ Bsh,
    unsigned short* __restrict__ Y, int M) {
  __shared__ unsigned short As[BM * LDK];
  __shared__ unsigned short Bs[BN * LDK];
  int t = threadIdx.x;
  int m0 = blockIdx.x * BM;
  int n0 = blockIdx.y * BN;
  int l = t & 63, w = t >> 6;
  int wm = w & 1, wn = w >> 1;
  int cl = l & 15, q = l >> 4;
  int r0 = t >> 2;
  int kc = (t & 3) * 8;

  f32x4 acc[4][4];
  f32x4 zf = {0.f, 0.f, 0.f, 0.f};
#pragma unroll
  for (int i = 0; i < 4; ++i)
#pragma unroll
    for (int jj = 0; jj < 4; ++jj) acc[i][jj] = zf;

  int arow0 = m0 + r0;      if (arow0 > M - 1) arow0 = M - 1;
  int arow1 = m0 + r0 + 64; if (arow1 > M - 1) arow1 = M - 1;
  int brow0 = n0 + r0, brow1 = n0 + r0 + 64;

  for (int k0 = 0; k0 < HDIM; k0 += BK) {
    uint4 a0 = *reinterpret_cast<const uint4*>(&Xb[(size_t)arow0 * HDIM + k0 + kc]);
    uint4 a1 = *reinterpret_cast<const uint4*>(&Xb[(size_t)arow1 * HDIM + k0 + kc]);
    uint4 b0 = *reinterpret_cast<const uint4*>(&Wt[(size_t)brow0 * HDIM + k0 + kc]);
    uint4 b1 = *reinterpret_cast<const uint4*>(&Wt[(size_t)brow1 * HDIM + k0 + kc]);
    __syncthreads();
    *reinterpret_cast<uint4*>(&As[r0 * LDK + kc]) = a0;
    *reinterpret_cast<uint4*>(&As[(r0 + 64) * LDK + kc]) = a1;
    *reinterpret_cast<uint4*>(&Bs[r0 * LDK + kc]) = b0;
    *reinterpret_cast<uint4*>(&Bs[(r0 + 64) * LDK + kc]) = b1;
    __syncthreads();
    bf16x8 af[4], bfr[4];
#pragma unroll
    for (int i = 0; i < 4; ++i)
      af[i] = *reinterpret_cast<const bf16x8*>(&As[(wm * 64 + i * 16 + cl) * LDK + q * 8]);
#pragma unroll
    for (int jj = 0; jj < 4; ++jj)
      bfr[jj] = *reinterpret_cast<const bf16x8*>(&Bs[(wn * 64 + jj * 16 + cl) * LDK + q * 8]);
#pragma unroll
    for (int i = 0; i < 4; ++i)
#pragma unroll
      for (int jj = 0; jj < 4; ++jj)
        acc[i][jj] = __builtin_amdgcn_mfma_f32_16x16x32_bf16(af[i], bfr[jj], acc[i][jj], 0, 0, 0);
  }

#pragma unroll
  for (int jj = 0; jj < 4; ++jj) {
    int col = n0 + wn * 64 + jj * 16 + cl;
    float as = Asc[col], bsv = Bsh[col];
#pragma unroll
    for (int i = 0; i < 4; ++i) {
      int rowb = m0 + wm * 64 + i * 16 + q * 4;
#pragma unroll
      for (int r = 0; r < 4; ++r) {
        int row = rowb + r;
        if (row < M)
          Y[(size_t)row * HDIM + col] = f2bf(fmaxf(fmaf(acc[i][jj][r], as, bsv), 0.f));
      }
    }
  }
}

// ---------- pooling ----------

__global__ void k_goff(const int* __restrict__ batch, int* __restrict__ goff, int G, int n) {
  int g = blockIdx.x * 256 + threadIdx.x;
  if (g > G) return;
  int lo = 0, hi = n;
  while (lo < hi) {
    int mid = (lo + hi) >> 1;
    if (batch[mid] < g) lo = mid + 1;
    else hi = mid;
  }
  goff[g] = lo;
}

__global__ __launch_bounds__(256) void k_pool(
    const unsigned short* __restrict__ X, const int* __restrict__ goff,
    float* __restrict__ P, int G) {
  int g = blockIdx.x * 4 + (threadIdx.x >> 6);
  if (g >= G) return;
  int j = (threadIdx.x & 63) * 4;
  int r0 = goff[g], r1 = goff[g + 1];
  float4 acc = make_float4(0.f, 0.f, 0.f, 0.f);
  for (int r = r0; r < r1; ++r) {
    ushort4 x4 = *reinterpret_cast<const ushort4*>(&X[(size_t)r * HDIM + j]);
    acc.x += bf2f(x4.x); acc.y += bf2f(x4.y); acc.z += bf2f(x4.z); acc.w += bf2f(x4.w);
  }
  float inv = 1.f / fmaxf((float)(r1 - r0), 1.f);
  float4 o = make_float4(acc.x * inv, acc.y * inv, acc.z * inv, acc.w * inv);
  *reinterpret_cast<float4*>(&P[(size_t)g * HDIM + j]) = o;
}

// ---------- final projection ----------

__global__ __launch_bounds__(128) void k_proj(
    const float* __restrict__ P, const float* __restrict__ W,
    const float* __restrict__ bias, float* __restrict__ out, int G) {
  __shared__ float rows[8][HDIM];
  int g0 = blockIdx.x * 8;
  for (int i = threadIdx.x; i < 8 * HDIM; i += 128) {
    int g = g0 + (i >> 8);
    rows[i >> 8][i & 255] = (g < G) ? P[(size_t)g * HDIM + (i & 255)] : 0.f;
  }
  __syncthreads();
  int d = threadIdx.x;
  float bb = bias[d];
  float acc[8] = {bb, bb, bb, bb, bb, bb, bb, bb};
  for (int k = 0; k < HDIM; ++k) {
    float w = W[(size_t)k * DDIM + d];
#pragma unroll
    for (int q = 0; q < 8; ++q) acc[q] = fmaf(rows[q][k], w, acc[q]);
  }
#pragma unroll
  for (int q = 0; q < 8; ++q) {
    int g = g0 + q;
    if (g < G) out[(size_t)g * DDIM + d] = acc[q];
  }
}

// ---------- launch ----------

extern "C" void kernel_launch(void* const* d_in, const int* in_sizes, int n_in,
                              void* d_out, int out_size, void* d_ws, size_t ws_size,
                              hipStream_t stream) {
  const int N = in_sizes[0];
  const int E = in_sizes[1] / 2;
  const int G = out_size / DDIM;

  const int* node_ids = (const int*)d_in[0];
  const int* src = (const int*)d_in[1];
  const int* dst = src + E;
  const int* batch = (const int*)d_in[2];
  const float* emb = (const float*)d_in[3];
  const float* Ws = (const float*)d_in[4];
  const float* bs = (const float*)d_in[5];
  const float* gam = (const float*)d_in[6];
  const float* bet = (const float*)d_in[7];
  const float* mu = (const float*)d_in[8];
  const float* va = (const float*)d_in[9];
  const float* pW = (const float*)d_in[10];
  const float* pb = (const float*)d_in[11];
  float* out = (float*)d_out;

  size_t o = 0;
  auto alloc = [&](size_t bytes) -> void* {
    size_t start = (o + 255) & ~(size_t)255;
    o = start + bytes;
    return (void*)((char*)d_ws + start);
  };
  int NB = (N + 255) / 256;
  int* cnt = (int*)alloc((size_t)N * 4);
  float* dinv = (float*)alloc((size_t)N * 4);
  int* off = (int*)alloc((size_t)(N + 1) * 4);
  int* bsum = (int*)alloc((size_t)NB * 4);
  int4* edata = (int4*)alloc((size_t)E * 16);
  float* embW = (float*)alloc((size_t)VSZ * HDIM * 4);
  float* Ac = (float*)alloc((size_t)3 * HDIM * 4);
  float* Bc = (float*)alloc((size_t)3 * HDIM * 4);
  int* goff = (int*)alloc((size_t)(G + 1) * 4);
  unsigned short* Wtb = (unsigned short*)alloc((size_t)2 * HDIM * HDIM * 2);
  unsigned short* bufX = (unsigned short*)alloc((size_t)N * HDIM * 2);
  unsigned short* bufY = (unsigned short*)alloc((size_t)N * HDIM * 2);
  float* pooled = (float*)alloc((size_t)G * HDIM * 4);

  int gE = (E + 255) / 256;
  int gN = (N + 255) / 256;

  // CSR build
  hipMemsetAsync(cnt, 0, (size_t)N * 4, stream);
  k_count<<<gE, 256, 0, stream>>>(dst, cnt, E);
  k_dinv<<<gN, 256, 0, stream>>>(cnt, dinv, N);
  k_scan_chunk<<<NB, 256, 0, stream>>>(cnt, off, bsum, N);
  k_scan_bsum<<<1, 64, 0, stream>>>(bsum, NB);
  k_scan_add<<<(N + 1 + 255) / 256, 256, 0, stream>>>(off, bsum, N, E);
  hipMemsetAsync(cnt, 0, (size_t)N * 4, stream);
  k_fill<<<gE, 256, 0, stream>>>(src, dst, node_ids, dinv, off, cnt, edata, E);

  // tiny precomputes
  k_embw<<<VSZ, HDIM, 0, stream>>>(emb, Ws, embW);
  k_bnc<<<3, HDIM, 0, stream>>>(bs, gam, bet, mu, va, Ac, Bc);
  dim3 tg(8, 8);
  k_wcvt<<<tg, 256, 0, stream>>>(Ws + 1 * HDIM * HDIM, Wtb);
  k_wcvt<<<tg, 256, 0, stream>>>(Ws + 2 * HDIM * HDIM, Wtb + HDIM * HDIM);

  // layer 1 (fused: aggregate 14-row table + BN + ReLU) -> bf16
  k_layer1<<<(N + 3) / 4, 256, 0, stream>>>(node_ids, embW, off, edata, dinv,
                                            Ac, Bc, bufX, N);

  // layers 2,3: aggregate (bf16) then MFMA GEMM + BN + ReLU (bf16)
  dim3 gg((N + BM - 1) / BM, HDIM / BN);
  k_agg<<<(N + 3) / 4, 256, 0, stream>>>(bufX, off, edata, dinv, bufY, N);
  k_gemm_mfma<<<gg, 256, 0, stream>>>(bufY, Wtb, Ac + HDIM, Bc + HDIM, bufX, N);
  k_agg<<<(N + 3) / 4, 256, 0, stream>>>(bufX, off, edata, dinv, bufY, N);
  k_gemm_mfma<<<gg, 256, 0, stream>>>(bufY, Wtb + HDIM * HDIM, Ac + 2 * HDIM, Bc + 2 * HDIM, bufX, N);

  // pooling + projection
  k_goff<<<(G + 1 + 255) / 256, 256, 0, stream>>>(batch, goff, G, N);
  k_pool<<<(G + 3) / 4, 256, 0, stream>>>(bufX, goff, pooled, G);
  k_proj<<<(G + 7) / 8, 128, 0, stream>>>(pooled, pW, pb, out, G);
}

// Round 4
// 363.525 us; speedup vs baseline: 1.9613x; 1.0749x over previous
//
#include <hip/hip_runtime.h>

#define HDIM 256
#define DDIM 128
#define VSZ 14

typedef __bf16 bf16x8 __attribute__((ext_vector_type(8)));
typedef float f32x4 __attribute__((ext_vector_type(4)));

static __device__ __forceinline__ unsigned short f2bf(float f) {
  unsigned u = __builtin_bit_cast(unsigned, f);
  u += 0x7FFF + ((u >> 16) & 1);  // round-to-nearest-even
  return (unsigned short)(u >> 16);
}
static __device__ __forceinline__ float bf2f(unsigned short u) {
  unsigned x = ((unsigned)u) << 16;
  return __builtin_bit_cast(float, x);
}
static __device__ __forceinline__ unsigned pack2(float a, float b) {
  return (unsigned)f2bf(a) | ((unsigned)f2bf(b) << 16);
}
// unpack 8 bf16 (as uint4) -> 8 f32
static __device__ __forceinline__ void ub8(uint4 p, float* o) {
  o[0] = __builtin_bit_cast(float, p.x << 16);
  o[1] = __builtin_bit_cast(float, p.x & 0xFFFF0000u);
  o[2] = __builtin_bit_cast(float, p.y << 16);
  o[3] = __builtin_bit_cast(float, p.y & 0xFFFF0000u);
  o[4] = __builtin_bit_cast(float, p.z << 16);
  o[5] = __builtin_bit_cast(float, p.z & 0xFFFF0000u);
  o[6] = __builtin_bit_cast(float, p.w << 16);
  o[7] = __builtin_bit_cast(float, p.w & 0xFFFF0000u);
}

// ---------- degree / CSR construction ----------

__global__ void k_count(const int* __restrict__ dst, int* __restrict__ cnt, int E) {
  int i = blockIdx.x * 256 + threadIdx.x;
  if (i < E) atomicAdd(&cnt[dst[i]], 1);
}

__global__ void k_dinv(const int* __restrict__ cnt, float* __restrict__ dinv, int n) {
  int i = blockIdx.x * 256 + threadIdx.x;
  if (i < n) dinv[i] = rsqrtf((float)(cnt[i] + 1));  // +1 self-loop
}

__global__ void k_scan_chunk(const int* __restrict__ cnt, int* __restrict__ off,
                             int* __restrict__ bsum, int n) {
  __shared__ int s[256];
  int i = blockIdx.x * 256 + threadIdx.x;
  int v = (i < n) ? cnt[i] : 0;
  s[threadIdx.x] = v;
  __syncthreads();
  for (int d = 1; d < 256; d <<= 1) {
    int add = (threadIdx.x >= d) ? s[threadIdx.x - d] : 0;
    __syncthreads();
    s[threadIdx.x] += add;
    __syncthreads();
  }
  if (i < n) off[i] = s[threadIdx.x] - v;
  if (threadIdx.x == 255) bsum[blockIdx.x] = s[255];
}

__global__ void k_scan_bsum(int* bsum, int nb) {
  if (threadIdx.x == 0) {
    int acc = 0;
    for (int b = 0; b < nb; ++b) { int t = bsum[b]; bsum[b] = acc; acc += t; }
  }
}

__global__ void k_scan_add(int* __restrict__ off, const int* __restrict__ bsum, int n, int E) {
  int i = blockIdx.x * 256 + threadIdx.x;
  if (i < n) off[i] += bsum[i >> 8];
  else if (i == n) off[n] = E;
}

// packed edge record: {src, id(src), dinv(src) bits, 0}
__global__ void k_fill(const int* __restrict__ src, const int* __restrict__ dst,
                       const int* __restrict__ ids, const float* __restrict__ dinv,
                       const int* __restrict__ off, int* __restrict__ cur,
                       int4* __restrict__ edata, int E) {
  int i = blockIdx.x * 256 + threadIdx.x;
  if (i >= E) return;
  int d = dst[i];
  int p = off[d] + atomicAdd(&cur[d], 1);
  int s = src[i];
  int4 v;
  v.x = s;
  v.y = ids[s];
  v.z = __builtin_bit_cast(int, dinv[s]);
  v.w = 0;
  edata[p] = v;
}

// ---------- tiny precomputes ----------

__global__ void k_embw(const float* __restrict__ emb, const float* __restrict__ W0,
                       float* __restrict__ embW) {
  int t = blockIdx.x, j = threadIdx.x;
  float acc = 0.f;
  for (int k = 0; k < HDIM; ++k) acc = fmaf(emb[t * HDIM + k], W0[k * HDIM + j], acc);
  embW[t * HDIM + j] = acc;
}

__global__ void k_bnc(const float* __restrict__ bs, const float* __restrict__ g,
                      const float* __restrict__ be, const float* __restrict__ mu,
                      const float* __restrict__ va, float* __restrict__ A,
                      float* __restrict__ B) {
  int i = blockIdx.x * HDIM + threadIdx.x;
  float a = g[i] * rsqrtf(va[i] + 1e-5f);
  A[i] = a;
  B[i] = (bs[i] - mu[i]) * a + be[i];
}

// transpose + convert W (256x256 f32, k-major) -> Wt (256x256 bf16, n-major)
__global__ __launch_bounds__(256) void k_wcvt(const float* __restrict__ W,
                                              unsigned short* __restrict__ Wt) {
  __shared__ float tile[32][33];
  int bx = blockIdx.x * 32, by = blockIdx.y * 32;
  int tx = threadIdx.x & 31, ty = threadIdx.x >> 5;
#pragma unroll
  for (int i = 0; i < 4; ++i)
    tile[ty + i * 8][tx] = W[(size_t)(by + ty + i * 8) * HDIM + bx + tx];
  __syncthreads();
#pragma unroll
  for (int i = 0; i < 4; ++i)
    Wt[(size_t)(bx + ty + i * 8) * HDIM + by + tx] = f2bf(tile[tx][ty + i * 8]);
}

// ---------- layer 1: aggregate bf16 14-row table (LDS) + BN + ReLU -> bf16 ----------
// half-wave per node: 32 lanes x 8 cols, 8 nodes/block

__global__ __launch_bounds__(256) void k_layer1(
    const int* __restrict__ ids, const float* __restrict__ embW,
    const int* __restrict__ off, const int4* __restrict__ edata,
    const float* __restrict__ dinv,
    const float* __restrict__ A, const float* __restrict__ B,
    unsigned short* __restrict__ Y, int n) {
  __shared__ unsigned short lw[VSZ * HDIM];
  for (int i = threadIdx.x; i < VSZ * HDIM; i += 256) lw[i] = f2bf(embW[i]);
  __syncthreads();
  int v = blockIdx.x * 8 + (threadIdx.x >> 5);
  if (v >= n) return;
  int j = (threadIdx.x & 31) * 8;
  float dv = dinv[v];
  float s = dv * dv;
  float acc[8], m[8];
  uint4 x = *reinterpret_cast<const uint4*>(&lw[ids[v] * HDIM + j]);
  ub8(x, acc);
#pragma unroll
  for (int i = 0; i < 8; ++i) acc[i] *= s;
  int e = off[v], e1 = off[v + 1];
  for (; e + 3 < e1; e += 4) {
    int4 d0 = edata[e], d1 = edata[e + 1], d2 = edata[e + 2], d3 = edata[e + 3];
    uint4 g0 = *reinterpret_cast<const uint4*>(&lw[d0.y * HDIM + j]);
    uint4 g1 = *reinterpret_cast<const uint4*>(&lw[d1.y * HDIM + j]);
    uint4 g2 = *reinterpret_cast<const uint4*>(&lw[d2.y * HDIM + j]);
    uint4 g3 = *reinterpret_cast<const uint4*>(&lw[d3.y * HDIM + j]);
    float w0 = dv * __builtin_bit_cast(float, d0.z);
    float w1 = dv * __builtin_bit_cast(float, d1.z);
    float w2 = dv * __builtin_bit_cast(float, d2.z);
    float w3 = dv * __builtin_bit_cast(float, d3.z);
    ub8(g0, m);
#pragma unroll
    for (int i = 0; i < 8; ++i) acc[i] = fmaf(w0, m[i], acc[i]);
    ub8(g1, m);
#pragma unroll
    for (int i = 0; i < 8; ++i) acc[i] = fmaf(w1, m[i], acc[i]);
    ub8(g2, m);
#pragma unroll
    for (int i = 0; i < 8; ++i) acc[i] = fmaf(w2, m[i], acc[i]);
    ub8(g3, m);
#pragma unroll
    for (int i = 0; i < 8; ++i) acc[i] = fmaf(w3, m[i], acc[i]);
  }
  for (; e < e1; ++e) {
    int4 d0 = edata[e];
    uint4 g0 = *reinterpret_cast<const uint4*>(&lw[d0.y * HDIM + j]);
    float w0 = dv * __builtin_bit_cast(float, d0.z);
    ub8(g0, m);
#pragma unroll
    for (int i = 0; i < 8; ++i) acc[i] = fmaf(w0, m[i], acc[i]);
  }
  float4 a0 = *reinterpret_cast<const float4*>(&A[j]);
  float4 a1 = *reinterpret_cast<const float4*>(&A[j + 4]);
  float4 b0 = *reinterpret_cast<const float4*>(&B[j]);
  float4 b1 = *reinterpret_cast<const float4*>(&B[j + 4]);
  float o[8];
  o[0] = fmaxf(fmaf(acc[0], a0.x, b0.x), 0.f);
  o[1] = fmaxf(fmaf(acc[1], a0.y, b0.y), 0.f);
  o[2] = fmaxf(fmaf(acc[2], a0.z, b0.z), 0.f);
  o[3] = fmaxf(fmaf(acc[3], a0.w, b0.w), 0.f);
  o[4] = fmaxf(fmaf(acc[4], a1.x, b1.x), 0.f);
  o[5] = fmaxf(fmaf(acc[5], a1.y, b1.y), 0.f);
  o[6] = fmaxf(fmaf(acc[6], a1.z, b1.z), 0.f);
  o[7] = fmaxf(fmaf(acc[7], a1.w, b1.w), 0.f);
  uint4 st;
  st.x = pack2(o[0], o[1]);
  st.y = pack2(o[2], o[3]);
  st.z = pack2(o[4], o[5]);
  st.w = pack2(o[6], o[7]);
  *reinterpret_cast<uint4*>(&Y[(size_t)v * HDIM + j]) = st;
}

// ---------- aggregation: bf16 gather -> bf16 out, half-wave per node ----------

__global__ __launch_bounds__(256) void k_agg(
    const unsigned short* __restrict__ X, const int* __restrict__ off,
    const int4* __restrict__ edata, const float* __restrict__ dinv,
    unsigned short* __restrict__ Yb, int n) {
  int v = blockIdx.x * 8 + (threadIdx.x >> 5);
  if (v >= n) return;
  int j = (threadIdx.x & 31) * 8;
  float dv = dinv[v];
  float s = dv * dv;
  float acc[8], m[8];
  uint4 x = *reinterpret_cast<const uint4*>(&X[(size_t)v * HDIM + j]);
  ub8(x, acc);
#pragma unroll
  for (int i = 0; i < 8; ++i) acc[i] *= s;
  int e = off[v], e1 = off[v + 1];
  for (; e + 3 < e1; e += 4) {
    int4 d0 = edata[e], d1 = edata[e + 1], d2 = edata[e + 2], d3 = edata[e + 3];
    uint4 g0 = *reinterpret_cast<const uint4*>(&X[(size_t)d0.x * HDIM + j]);
    uint4 g1 = *reinterpret_cast<const uint4*>(&X[(size_t)d1.x * HDIM + j]);
    uint4 g2 = *reinterpret_cast<const uint4*>(&X[(size_t)d2.x * HDIM + j]);
    uint4 g3 = *reinterpret_cast<const uint4*>(&X[(size_t)d3.x * HDIM + j]);
    float w0 = dv * __builtin_bit_cast(float, d0.z);
    float w1 = dv * __builtin_bit_cast(float, d1.z);
    float w2 = dv * __builtin_bit_cast(float, d2.z);
    float w3 = dv * __builtin_bit_cast(float, d3.z);
    ub8(g0, m);
#pragma unroll
    for (int i = 0; i < 8; ++i) acc[i] = fmaf(w0, m[i], acc[i]);
    ub8(g1, m);
#pragma unroll
    for (int i = 0; i < 8; ++i) acc[i] = fmaf(w1, m[i], acc[i]);
    ub8(g2, m);
#pragma unroll
    for (int i = 0; i < 8; ++i) acc[i] = fmaf(w2, m[i], acc[i]);
    ub8(g3, m);
#pragma unroll
    for (int i = 0; i < 8; ++i) acc[i] = fmaf(w3, m[i], acc[i]);
  }
  for (; e < e1; ++e) {
    int4 d0 = edata[e];
    uint4 g0 = *reinterpret_cast<const uint4*>(&X[(size_t)d0.x * HDIM + j]);
    float w0 = dv * __builtin_bit_cast(float, d0.z);
    ub8(g0, m);
#pragma unroll
    for (int i = 0; i < 8; ++i) acc[i] = fmaf(w0, m[i], acc[i]);
  }
  uint4 st;
  st.x = pack2(acc[0], acc[1]);
  st.y = pack2(acc[2], acc[3]);
  st.z = pack2(acc[4], acc[5]);
  st.w = pack2(acc[6], acc[7]);
  *reinterpret_cast<uint4*>(&Yb[(size_t)v * HDIM + j]) = st;
}

// ---------- bf16 MFMA GEMM (M x 256) @ (256 x 256) + BN + ReLU -> bf16 ----------

#define BM 128
#define BN 128
#define BK 32
#define LDK 40  // padded LDS row stride (elements)

__global__ __launch_bounds__(256) void k_gemm_mfma(
    const unsigned short* __restrict__ Xb, const unsigned short* __restrict__ Wt,
    const float* __restrict__ Asc, const float* __restrict__ Bsh,
    unsigned short* __restrict__ Y, int M) {
  __shared__ unsigned short As[BM * LDK];
  __shared__ unsigned short Bs[BN * LDK];
  int t = threadIdx.x;
  int m0 = blockIdx.x * BM;
  int n0 = blockIdx.y * BN;
  int l = t & 63, w = t >> 6;
  int wm = w & 1, wn = w >> 1;
  int cl = l & 15, q = l >> 4;
  int r0 = t >> 2;
  int kc = (t & 3) * 8;

  f32x4 acc[4][4];
  f32x4 zf = {0.f, 0.f, 0.f, 0.f};
#pragma unroll
  for (int i = 0; i < 4; ++i)
#pragma unroll
    for (int jj = 0; jj < 4; ++jj) acc[i][jj] = zf;

  int arow0 = m0 + r0;      if (arow0 > M - 1) arow0 = M - 1;
  int arow1 = m0 + r0 + 64; if (arow1 > M - 1) arow1 = M - 1;
  int brow0 = n0 + r0, brow1 = n0 + r0 + 64;

  for (int k0 = 0; k0 < HDIM; k0 += BK) {
    uint4 a0 = *reinterpret_cast<const uint4*>(&Xb[(size_t)arow0 * HDIM + k0 + kc]);
    uint4 a1 = *reinterpret_cast<const uint4*>(&Xb[(size_t)arow1 * HDIM + k0 + kc]);
    uint4 b0 = *reinterpret_cast<const uint4*>(&Wt[(size_t)brow0 * HDIM + k0 + kc]);
    uint4 b1 = *reinterpret_cast<const uint4*>(&Wt[(size_t)brow1 * HDIM + k0 + kc]);
    __syncthreads();
    *reinterpret_cast<uint4*>(&As[r0 * LDK + kc]) = a0;
    *reinterpret_cast<uint4*>(&As[(r0 + 64) * LDK + kc]) = a1;
    *reinterpret_cast<uint4*>(&Bs[r0 * LDK + kc]) = b0;
    *reinterpret_cast<uint4*>(&Bs[(r0 + 64) * LDK + kc]) = b1;
    __syncthreads();
    bf16x8 af[4], bfr[4];
#pragma unroll
    for (int i = 0; i < 4; ++i)
      af[i] = *reinterpret_cast<const bf16x8*>(&As[(wm * 64 + i * 16 + cl) * LDK + q * 8]);
#pragma unroll
    for (int jj = 0; jj < 4; ++jj)
      bfr[jj] = *reinterpret_cast<const bf16x8*>(&Bs[(wn * 64 + jj * 16 + cl) * LDK + q * 8]);
#pragma unroll
    for (int i = 0; i < 4; ++i)
#pragma unroll
      for (int jj = 0; jj < 4; ++jj)
        acc[i][jj] = __builtin_amdgcn_mfma_f32_16x16x32_bf16(af[i], bfr[jj], acc[i][jj], 0, 0, 0);
  }

#pragma unroll
  for (int jj = 0; jj < 4; ++jj) {
    int col = n0 + wn * 64 + jj * 16 + cl;
    float as = Asc[col], bsv = Bsh[col];
#pragma unroll
    for (int i = 0; i < 4; ++i) {
      int rowb = m0 + wm * 64 + i * 16 + q * 4;
#pragma unroll
      for (int r = 0; r < 4; ++r) {
        int row = rowb + r;
        if (row < M)
          Y[(size_t)row * HDIM + col] = f2bf(fmaxf(fmaf(acc[i][jj][r], as, bsv), 0.f));
      }
    }
  }
}

// ---------- pooling: half-wave per graph ----------

__global__ void k_goff(const int* __restrict__ batch, int* __restrict__ goff, int G, int n) {
  int g = blockIdx.x * 256 + threadIdx.x;
  if (g > G) return;
  int lo = 0, hi = n;
  while (lo < hi) {
    int mid = (lo + hi) >> 1;
    if (batch[mid] < g) lo = mid + 1;
    else hi = mid;
  }
  goff[g] = lo;
}

__global__ __launch_bounds__(256) void k_pool(
    const unsigned short* __restrict__ X, const int* __restrict__ goff,
    float* __restrict__ P, int G) {
  int g = blockIdx.x * 8 + (threadIdx.x >> 5);
  if (g >= G) return;
  int j = (threadIdx.x & 31) * 8;
  int r0 = goff[g], r1 = goff[g + 1];
  float acc[8] = {0.f, 0.f, 0.f, 0.f, 0.f, 0.f, 0.f, 0.f};
  float m[8];
  int r = r0;
  for (; r + 1 < r1; r += 2) {
    uint4 x0 = *reinterpret_cast<const uint4*>(&X[(size_t)r * HDIM + j]);
    uint4 x1 = *reinterpret_cast<const uint4*>(&X[(size_t)(r + 1) * HDIM + j]);
    ub8(x0, m);
#pragma unroll
    for (int i = 0; i < 8; ++i) acc[i] += m[i];
    ub8(x1, m);
#pragma unroll
    for (int i = 0; i < 8; ++i) acc[i] += m[i];
  }
  if (r < r1) {
    uint4 x0 = *reinterpret_cast<const uint4*>(&X[(size_t)r * HDIM + j]);
    ub8(x0, m);
#pragma unroll
    for (int i = 0; i < 8; ++i) acc[i] += m[i];
  }
  float inv = 1.f / fmaxf((float)(r1 - r0), 1.f);
  float4 o0 = make_float4(acc[0] * inv, acc[1] * inv, acc[2] * inv, acc[3] * inv);
  float4 o1 = make_float4(acc[4] * inv, acc[5] * inv, acc[6] * inv, acc[7] * inv);
  *reinterpret_cast<float4*>(&P[(size_t)g * HDIM + j]) = o0;
  *reinterpret_cast<float4*>(&P[(size_t)g * HDIM + j + 4]) = o1;
}

// ---------- final projection ----------

__global__ __launch_bounds__(128) void k_proj(
    const float* __restrict__ P, const float* __restrict__ W,
    const float* __restrict__ bias, float* __restrict__ out, int G) {
  __shared__ float rows[8][HDIM];
  int g0 = blockIdx.x * 8;
  for (int i = threadIdx.x; i < 8 * HDIM; i += 128) {
    int g = g0 + (i >> 8);
    rows[i >> 8][i & 255] = (g < G) ? P[(size_t)g * HDIM + (i & 255)] : 0.f;
  }
  __syncthreads();
  int d = threadIdx.x;
  float bb = bias[d];
  float acc[8] = {bb, bb, bb, bb, bb, bb, bb, bb};
  for (int k = 0; k < HDIM; ++k) {
    float w = W[(size_t)k * DDIM + d];
#pragma unroll
    for (int q = 0; q < 8; ++q) acc[q] = fmaf(rows[q][k], w, acc[q]);
  }
#pragma unroll
  for (int q = 0; q < 8; ++q) {
    int g = g0 + q;
    if (g < G) out[(size_t)g * DDIM + d] = acc[q];
  }
}

// ---------- launch ----------

extern "C" void kernel_launch(void* const* d_in, const int* in_sizes, int n_in,
                              void* d_out, int out_size, void* d_ws, size_t ws_size,
                              hipStream_t stream) {
  const int N = in_sizes[0];
  const int E = in_sizes[1] / 2;
  const int G = out_size / DDIM;

  const int* node_ids = (const int*)d_in[0];
  const int* src = (const int*)d_in[1];
  const int* dst = src + E;
  const int* batch = (const int*)d_in[2];
  const float* emb = (const float*)d_in[3];
  const float* Ws = (const float*)d_in[4];
  const float* bs = (const float*)d_in[5];
  const float* gam = (const float*)d_in[6];
  const float* bet = (const float*)d_in[7];
  const float* mu = (const float*)d_in[8];
  const float* va = (const float*)d_in[9];
  const float* pW = (const float*)d_in[10];
  const float* pb = (const float*)d_in[11];
  float* out = (float*)d_out;

  size_t o = 0;
  auto alloc = [&](size_t bytes) -> void* {
    size_t start = (o + 255) & ~(size_t)255;
    o = start + bytes;
    return (void*)((char*)d_ws + start);
  };
  int NB = (N + 255) / 256;
  int* cnt = (int*)alloc((size_t)N * 4);
  float* dinv = (float*)alloc((size_t)N * 4);
  int* off = (int*)alloc((size_t)(N + 1) * 4);
  int* bsum = (int*)alloc((size_t)NB * 4);
  int4* edata = (int4*)alloc((size_t)E * 16);
  float* embW = (float*)alloc((size_t)VSZ * HDIM * 4);
  float* Ac = (float*)alloc((size_t)3 * HDIM * 4);
  float* Bc = (float*)alloc((size_t)3 * HDIM * 4);
  int* goff = (int*)alloc((size_t)(G + 1) * 4);
  unsigned short* Wtb = (unsigned short*)alloc((size_t)2 * HDIM * HDIM * 2);
  unsigned short* bufX = (unsigned short*)alloc((size_t)N * HDIM * 2);
  unsigned short* bufY = (unsigned short*)alloc((size_t)N * HDIM * 2);
  float* pooled = (float*)alloc((size_t)G * HDIM * 4);

  int gE = (E + 255) / 256;
  int gN = (N + 255) / 256;

  // CSR build
  hipMemsetAsync(cnt, 0, (size_t)N * 4, stream);
  k_count<<<gE, 256, 0, stream>>>(dst, cnt, E);
  k_dinv<<<gN, 256, 0, stream>>>(cnt, dinv, N);
  k_scan_chunk<<<NB, 256, 0, stream>>>(cnt, off, bsum, N);
  k_scan_bsum<<<1, 64, 0, stream>>>(bsum, NB);
  k_scan_add<<<(N + 1 + 255) / 256, 256, 0, stream>>>(off, bsum, N, E);
  hipMemsetAsync(cnt, 0, (size_t)N * 4, stream);
  k_fill<<<gE, 256, 0, stream>>>(src, dst, node_ids, dinv, off, cnt, edata, E);

  // tiny precomputes
  k_embw<<<VSZ, HDIM, 0, stream>>>(emb, Ws, embW);
  k_bnc<<<3, HDIM, 0, stream>>>(bs, gam, bet, mu, va, Ac, Bc);
  dim3 tg(8, 8);
  k_wcvt<<<tg, 256, 0, stream>>>(Ws + 1 * HDIM * HDIM, Wtb);
  k_wcvt<<<tg, 256, 0, stream>>>(Ws + 2 * HDIM * HDIM, Wtb + HDIM * HDIM);

  // layer 1 (fused: aggregate 14-row table + BN + ReLU) -> bf16
  k_layer1<<<(N + 7) / 8, 256, 0, stream>>>(node_ids, embW, off, edata, dinv,
                                            Ac, Bc, bufX, N);

  // layers 2,3: aggregate (bf16) then MFMA GEMM + BN + ReLU (bf16)
  dim3 gg((N + BM - 1) / BM, HDIM / BN);
  k_agg<<<(N + 7) / 8, 256, 0, stream>>>(bufX, off, edata, dinv, bufY, N);
  k_gemm_mfma<<<gg, 256, 0, stream>>>(bufY, Wtb, Ac + HDIM, Bc + HDIM, bufX, N);
  k_agg<<<(N + 7) / 8, 256, 0, stream>>>(bufX, off, edata, dinv, bufY, N);
  k_gemm_mfma<<<gg, 256, 0, stream>>>(bufY, Wtb + HDIM * HDIM, Ac + 2 * HDIM, Bc + 2 * HDIM, bufX, N);

  // pooling + projection
  k_goff<<<(G + 1 + 255) / 256, 256, 0, stream>>>(batch, goff, G, N);
  k_pool<<<(G + 7) / 8, 256, 0, stream>>>(bufX, goff, pooled, G);
  k_proj<<<(G + 7) / 8, 128, 0, stream>>>(pooled, pW, pb, out, G);
}